// Round 5
// baseline (811.986 us; speedup 1.0000x reference)
//
#include <hip/hip_runtime.h>
#include <math.h>

#define EMBED 64
#define WPAD 68  // W row stride in LDS floats (pad +4 -> conflict-free b128)

// out[0] = h0 (layer-0 embedding), straight float4 copy
__global__ void copy_h0_kernel(const float* __restrict__ h0, float* __restrict__ out, int n4) {
    int i = blockIdx.x * blockDim.x + threadIdx.x;
    if (i < n4) ((float4*)out)[i] = ((const float4*)h0)[i];
}

// edge_row is sorted ascending -> build CSR row_ptr[N+1] by boundary scatter
__global__ void build_rowptr_kernel(const int* __restrict__ row, int* __restrict__ rp, int E, int N) {
    int i = blockIdx.x * blockDim.x + threadIdx.x;
    if (i >= E) return;
    if (i == 0) {
        int r0 = row[0];
        for (int r = 0; r <= r0; ++r) rp[r] = 0;
    } else {
        int a = row[i - 1], b = row[i];
        for (int r = a + 1; r <= b; ++r) rp[r] = i;
    }
    if (i == E - 1) {
        int rl = row[E - 1];
        for (int r = rl + 1; r <= N; ++r) rp[r] = E;
    }
}

// one LANE per edge: logits[e] = dot(h_att[row[e]], t_att[col[e]])
__global__ void __launch_bounds__(256) edge_logits_kernel(
        const float* __restrict__ ha, const float* __restrict__ ta,
        const int* __restrict__ row, const int* __restrict__ col,
        float* __restrict__ logits, int E) {
    int e = blockIdx.x * blockDim.x + threadIdx.x;
    if (e >= E) return;
    const float4* ha4 = (const float4*)(ha + (size_t)row[e] * EMBED);
    const float4* ta4 = (const float4*)(ta + (size_t)col[e] * EMBED);
    float4 acc = make_float4(0.f, 0.f, 0.f, 0.f);
    #pragma unroll
    for (int q = 0; q < 16; ++q) {
        float4 a = ha4[q];
        float4 t = ta4[q];
        acc.x = fmaf(a.x, t.x, acc.x);
        acc.y = fmaf(a.y, t.y, acc.y);
        acc.z = fmaf(a.z, t.z, acc.z);
        acc.w = fmaf(a.w, t.w, acc.w);
    }
    logits[e] = (acc.x + acc.y) + (acc.z + acc.w);
}

// one WAVE per node: softmax over CSR range, in-place logits -> weights.
__global__ void __launch_bounds__(256) node_softmax_kernel(
        const int* __restrict__ rp, float* __restrict__ lw, int N) {
    int n = (blockIdx.x * blockDim.x + threadIdx.x) >> 6;
    int lane = threadIdx.x & 63;
    if (n >= N) return;
    int s = rp[n], t = rp[n + 1];
    int deg = t - s;
    if (deg <= 0) return;

    if (deg <= 64) {
        float v = (lane < deg) ? lw[s + lane] : -INFINITY;
        float m = v;
        #pragma unroll
        for (int off = 32; off > 0; off >>= 1) m = fmaxf(m, __shfl_xor(m, off));
        float e = (lane < deg) ? expf(v - m) : 0.f;
        float sum = e;
        #pragma unroll
        for (int off = 32; off > 0; off >>= 1) sum += __shfl_xor(sum, off);
        float inv = 1.f / fmaxf(sum, 1e-12f);
        if (lane < deg) lw[s + lane] = e * inv;
    } else {
        float m = -INFINITY;
        for (int e = s + lane; e < t; e += 64) m = fmaxf(m, lw[e]);
        #pragma unroll
        for (int off = 32; off > 0; off >>= 1) m = fmaxf(m, __shfl_xor(m, off));
        float sum = 0.f;
        for (int e = s + lane; e < t; e += 64) sum += expf(lw[e] - m);
        #pragma unroll
        for (int off = 32; off > 0; off >>= 1) sum += __shfl_xor(sum, off);
        float inv = 1.f / fmaxf(sum, 1e-12f);
        for (int e = s + lane; e < t; e += 64) lw[e] = expf(lw[e] - m) * inv;
    }
}

// one wave per node (grid-stride): msg = sum_e w_e * h[col_e]; add = h[n]+msg;
// x = relu(add @ W^T + b); out = x / max(||x||, eps)
// R3 gather structure (8-deep dword gathers, wave-uniform col/ew) but W lives
// in LDS (row-major, +4 pad) instead of 64 VGPRs -> launch_bounds(256,8) for
// 8 waves/SIMD. Occupancy was the R3 limiter (21%, both pipes idle).
__global__ void __launch_bounds__(256, 8) prop_layer_kernel(
        const float* __restrict__ h_in,
        const float* __restrict__ W, const float* __restrict__ b,
        const int* __restrict__ col, const float* __restrict__ ew,
        const int* __restrict__ rp,
        float* __restrict__ out, int N, int totalWaves) {
    __shared__ float WL[EMBED * WPAD];

    int tid = threadIdx.x;
    // cooperative W load: 256 threads x 4 float4 = 4096 floats
    {
        const float4* Wg = (const float4*)W;
        #pragma unroll
        for (int q = 0; q < 4; ++q) {
            int idx4 = q * 256 + tid;       // float4 index 0..1023
            int flat = idx4 * 4;            // float index
            int i = flat >> 6, j = flat & 63;
            *(float4*)&WL[i * WPAD + j] = Wg[idx4];
        }
    }
    __syncthreads();

    int wid = (blockIdx.x * blockDim.x + tid) >> 6;
    int lane = tid & 63;
    float bias = b[lane];
    const float* hlane = h_in + lane;

    for (int n = wid; n < N; n += totalWaves) {
        int s = rp[n], t = rp[n + 1];
        float self = hlane[(size_t)n * EMBED];  // overlaps with gathers

        float acc0 = 0.f, acc1 = 0.f, acc2 = 0.f, acc3 = 0.f;
        int e = s;
        for (; e + 8 <= t; e += 8) {
            int c0 = col[e+0], c1 = col[e+1], c2 = col[e+2], c3 = col[e+3];
            int c4 = col[e+4], c5 = col[e+5], c6 = col[e+6], c7 = col[e+7];
            float w0 = ew[e+0], w1 = ew[e+1], w2 = ew[e+2], w3 = ew[e+3];
            float w4 = ew[e+4], w5 = ew[e+5], w6 = ew[e+6], w7 = ew[e+7];
            float v0 = hlane[(size_t)c0 * EMBED];
            float v1 = hlane[(size_t)c1 * EMBED];
            float v2 = hlane[(size_t)c2 * EMBED];
            float v3 = hlane[(size_t)c3 * EMBED];
            float v4 = hlane[(size_t)c4 * EMBED];
            float v5 = hlane[(size_t)c5 * EMBED];
            float v6 = hlane[(size_t)c6 * EMBED];
            float v7 = hlane[(size_t)c7 * EMBED];
            acc0 = fmaf(w0, v0, acc0);
            acc1 = fmaf(w1, v1, acc1);
            acc2 = fmaf(w2, v2, acc2);
            acc3 = fmaf(w3, v3, acc3);
            acc0 = fmaf(w4, v4, acc0);
            acc1 = fmaf(w5, v5, acc1);
            acc2 = fmaf(w6, v6, acc2);
            acc3 = fmaf(w7, v7, acc3);
        }
        for (; e + 4 <= t; e += 4) {
            int c0 = col[e+0], c1 = col[e+1], c2 = col[e+2], c3 = col[e+3];
            float w0 = ew[e+0], w1 = ew[e+1], w2 = ew[e+2], w3 = ew[e+3];
            float v0 = hlane[(size_t)c0 * EMBED];
            float v1 = hlane[(size_t)c1 * EMBED];
            float v2 = hlane[(size_t)c2 * EMBED];
            float v3 = hlane[(size_t)c3 * EMBED];
            acc0 = fmaf(w0, v0, acc0);
            acc1 = fmaf(w1, v1, acc1);
            acc2 = fmaf(w2, v2, acc2);
            acc3 = fmaf(w3, v3, acc3);
        }
        for (; e < t; ++e) {
            acc0 = fmaf(ew[e], hlane[(size_t)col[e] * EMBED], acc0);
        }
        float addv = self + ((acc0 + acc1) + (acc2 + acc3));

        float x = bias;
        #pragma unroll
        for (int jq = 0; jq < 16; ++jq) {
            float4 wv = *(const float4*)&WL[lane * WPAD + jq * 4];
            x = fmaf(__shfl(addv, 4 * jq + 0), wv.x, x);
            x = fmaf(__shfl(addv, 4 * jq + 1), wv.y, x);
            x = fmaf(__shfl(addv, 4 * jq + 2), wv.z, x);
            x = fmaf(__shfl(addv, 4 * jq + 3), wv.w, x);
        }
        x = fmaxf(x, 0.f);

        float ss = x * x;
        #pragma unroll
        for (int off = 32; off > 0; off >>= 1) ss += __shfl_xor(ss, off);
        float nrm = sqrtf(ss);
        float scale = 1.f / fmaxf(nrm, 1e-12f);
        out[(size_t)n * EMBED + lane] = x * scale;
    }
}

extern "C" void kernel_launch(void* const* d_in, const int* in_sizes, int n_in,
                              void* d_out, int out_size, void* d_ws, size_t ws_size,
                              hipStream_t stream) {
    const float* h0   = (const float*)d_in[0];
    const float* ha   = (const float*)d_in[1];
    const float* ta   = (const float*)d_in[2];
    const float* w1   = (const float*)d_in[3];
    const float* b1   = (const float*)d_in[4];
    const float* w2   = (const float*)d_in[5];
    const float* b2   = (const float*)d_in[6];
    const int*   erow = (const int*)d_in[7];
    const int*   ecol = (const int*)d_in[8];

    const int N = in_sizes[0] / EMBED;
    const int E = in_sizes[7];
    float* out = (float*)d_out;

    // workspace layout: row_ptr[N+1] ints, then edge weights[E] floats
    int*   rp = (int*)d_ws;
    size_t rp_bytes = ((size_t)(N + 1) * sizeof(int) + 255) & ~(size_t)255;
    float* ew = (float*)((char*)d_ws + rp_bytes);

    // 1. out[0] = h0
    {
        int n4 = N * EMBED / 4;
        copy_h0_kernel<<<(n4 + 255) / 256, 256, 0, stream>>>(h0, out, n4);
    }
    // 2. CSR row_ptr
    build_rowptr_kernel<<<(E + 255) / 256, 256, 0, stream>>>(erow, rp, E, N);
    // 3. edge logits (one lane/edge)
    edge_logits_kernel<<<(E + 255) / 256, 256, 0, stream>>>(ha, ta, erow, ecol, ew, E);
    // 4. per-node softmax (one wave/node, in-place logits -> weights)
    {
        int waves_per_block = 256 / 64;
        int blocks = (N + waves_per_block - 1) / waves_per_block;
        node_softmax_kernel<<<blocks, 256, 0, stream>>>(rp, ew, N);
    }

    // 5. layer 1: h0 -> out[1];  layer 2: out[1] -> out[2]
    const int blocks = 2048;
    const int totalWaves = blocks * (256 / 64);
    float* out1 = out + (size_t)N * EMBED;
    float* out2 = out + 2 * (size_t)N * EMBED;
    prop_layer_kernel<<<blocks, 256, 0, stream>>>(h0,   w1, b1, ecol, ew, rp, out1, N, totalWaves);
    prop_layer_kernel<<<blocks, 256, 0, stream>>>(out1, w2, b2, ecol, ew, rp, out2, N, totalWaves);
}

// Round 6
// 752.558 us; speedup vs baseline: 1.0790x; 1.0790x over previous
//
#include <hip/hip_runtime.h>
#include <math.h>

#define EMBED 64
#define WPAD 68  // W row stride in LDS floats (pad +4 -> conflict-free b128, verified 0 conflicts R5)

__device__ __forceinline__ unsigned short f32_to_bf16_rne(float f) {
    unsigned int u = __float_as_uint(f);
    unsigned int r = u + 0x7fffu + ((u >> 16) & 1u);
    return (unsigned short)(r >> 16);
}
__device__ __forceinline__ float bf16u_lo(unsigned int u) { return __uint_as_float(u << 16); }
__device__ __forceinline__ float bf16u_hi(unsigned int u) { return __uint_as_float(u & 0xffff0000u); }

// convert f32 -> packed bf16 (2 per uint), optionally also emit an f32 copy
// (used to fuse the out[0]=h0 copy). 8 floats per thread.
__global__ void __launch_bounds__(256) convert_bf16_kernel(
        const float* __restrict__ src, unsigned int* __restrict__ dstbf,
        float* __restrict__ copy_out, int n8) {
    int i = blockIdx.x * blockDim.x + threadIdx.x;
    if (i >= n8) return;
    const float4* s4 = (const float4*)src;
    float4 a = s4[2 * i], c = s4[2 * i + 1];
    uint4 p;
    p.x = (unsigned)f32_to_bf16_rne(a.x) | ((unsigned)f32_to_bf16_rne(a.y) << 16);
    p.y = (unsigned)f32_to_bf16_rne(a.z) | ((unsigned)f32_to_bf16_rne(a.w) << 16);
    p.z = (unsigned)f32_to_bf16_rne(c.x) | ((unsigned)f32_to_bf16_rne(c.y) << 16);
    p.w = (unsigned)f32_to_bf16_rne(c.z) | ((unsigned)f32_to_bf16_rne(c.w) << 16);
    ((uint4*)dstbf)[i] = p;
    if (copy_out) {
        float4* c4 = (float4*)copy_out;
        c4[2 * i] = a;
        c4[2 * i + 1] = c;
    }
}

// edge_row is sorted ascending -> build CSR row_ptr[N+1] by boundary scatter
__global__ void build_rowptr_kernel(const int* __restrict__ row, int* __restrict__ rp, int E, int N) {
    int i = blockIdx.x * blockDim.x + threadIdx.x;
    if (i >= E) return;
    if (i == 0) {
        int r0 = row[0];
        for (int r = 0; r <= r0; ++r) rp[r] = 0;
    } else {
        int a = row[i - 1], b = row[i];
        for (int r = a + 1; r <= b; ++r) rp[r] = i;
    }
    if (i == E - 1) {
        int rl = row[E - 1];
        for (int r = rl + 1; r <= N; ++r) rp[r] = E;
    }
}

// one LANE per edge, bf16 rows (128 B each): logits[e] = dot(ha[row[e]], ta[col[e]])
__global__ void __launch_bounds__(256) edge_logits_bf16_kernel(
        const unsigned int* __restrict__ hab, const unsigned int* __restrict__ tab,
        const int* __restrict__ row, const int* __restrict__ col,
        float* __restrict__ logits, int E) {
    int e = blockIdx.x * blockDim.x + threadIdx.x;
    if (e >= E) return;
    const uint4* a4 = (const uint4*)(hab + (size_t)row[e] * 32);
    const uint4* t4 = (const uint4*)(tab + (size_t)col[e] * 32);
    float acc = 0.f;
    #pragma unroll
    for (int q = 0; q < 8; ++q) {
        uint4 a = a4[q], t = t4[q];
        acc = fmaf(bf16u_lo(a.x), bf16u_lo(t.x), acc);
        acc = fmaf(bf16u_hi(a.x), bf16u_hi(t.x), acc);
        acc = fmaf(bf16u_lo(a.y), bf16u_lo(t.y), acc);
        acc = fmaf(bf16u_hi(a.y), bf16u_hi(t.y), acc);
        acc = fmaf(bf16u_lo(a.z), bf16u_lo(t.z), acc);
        acc = fmaf(bf16u_hi(a.z), bf16u_hi(t.z), acc);
        acc = fmaf(bf16u_lo(a.w), bf16u_lo(t.w), acc);
        acc = fmaf(bf16u_hi(a.w), bf16u_hi(t.w), acc);
    }
    logits[e] = acc;
}

// f32 fallback logits (used only if ws too small for bf16 tables)
__global__ void __launch_bounds__(256) edge_logits_kernel(
        const float* __restrict__ ha, const float* __restrict__ ta,
        const int* __restrict__ row, const int* __restrict__ col,
        float* __restrict__ logits, int E) {
    int e = blockIdx.x * blockDim.x + threadIdx.x;
    if (e >= E) return;
    const float4* ha4 = (const float4*)(ha + (size_t)row[e] * EMBED);
    const float4* ta4 = (const float4*)(ta + (size_t)col[e] * EMBED);
    float4 acc = make_float4(0.f, 0.f, 0.f, 0.f);
    #pragma unroll
    for (int q = 0; q < 16; ++q) {
        float4 a = ha4[q];
        float4 t = ta4[q];
        acc.x = fmaf(a.x, t.x, acc.x);
        acc.y = fmaf(a.y, t.y, acc.y);
        acc.z = fmaf(a.z, t.z, acc.z);
        acc.w = fmaf(a.w, t.w, acc.w);
    }
    logits[e] = (acc.x + acc.y) + (acc.z + acc.w);
}

// one WAVE per node: softmax over CSR range, in-place logits -> weights.
__global__ void __launch_bounds__(256) node_softmax_kernel(
        const int* __restrict__ rp, float* __restrict__ lw, int N) {
    int n = (blockIdx.x * blockDim.x + threadIdx.x) >> 6;
    int lane = threadIdx.x & 63;
    if (n >= N) return;
    int s = rp[n], t = rp[n + 1];
    int deg = t - s;
    if (deg <= 0) return;

    if (deg <= 64) {
        float v = (lane < deg) ? lw[s + lane] : -INFINITY;
        float m = v;
        #pragma unroll
        for (int off = 32; off > 0; off >>= 1) m = fmaxf(m, __shfl_xor(m, off));
        float e = (lane < deg) ? expf(v - m) : 0.f;
        float sum = e;
        #pragma unroll
        for (int off = 32; off > 0; off >>= 1) sum += __shfl_xor(sum, off);
        float inv = 1.f / fmaxf(sum, 1e-12f);
        if (lane < deg) lw[s + lane] = e * inv;
    } else {
        float m = -INFINITY;
        for (int e = s + lane; e < t; e += 64) m = fmaxf(m, lw[e]);
        #pragma unroll
        for (int off = 32; off > 0; off >>= 1) m = fmaxf(m, __shfl_xor(m, off));
        float sum = 0.f;
        for (int e = s + lane; e < t; e += 64) sum += expf(lw[e] - m);
        #pragma unroll
        for (int off = 32; off > 0; off >>= 1) sum += __shfl_xor(sum, off);
        float inv = 1.f / fmaxf(sum, 1e-12f);
        for (int e = s + lane; e < t; e += 64) lw[e] = expf(lw[e] - m) * inv;
    }
}

// one wave per node (grid-stride): msg = sum_e w_e * h[col_e]; add = h[n]+msg;
// x = relu(add @ W^T + b); out = x / max(||x||, eps)
// USEBF: gathers read a packed-bf16 table (128 B/row, halves L2-miss traffic —
// R5 showed the kernel is traffic-bound at high occupancy). Self row, W, b,
// ew stay f32. hbf_out optionally emits the bf16 copy of the result for the
// next layer's gathers.
template <bool USEBF>
__global__ void __launch_bounds__(256, 8) prop_layer_kernel(
        const float* __restrict__ h_in,
        const unsigned short* __restrict__ hbf,
        const float* __restrict__ W, const float* __restrict__ b,
        const int* __restrict__ col, const float* __restrict__ ew,
        const int* __restrict__ rp,
        float* __restrict__ out,
        unsigned short* __restrict__ hbf_out,
        int N, int totalWaves) {
    __shared__ float WL[EMBED * WPAD];

    int tid = threadIdx.x;
    {
        const float4* Wg = (const float4*)W;
        #pragma unroll
        for (int q = 0; q < 4; ++q) {
            int idx4 = q * 256 + tid;
            int flat = idx4 * 4;
            int i = flat >> 6, j = flat & 63;
            *(float4*)&WL[i * WPAD + j] = Wg[idx4];
        }
    }
    __syncthreads();

    int wid = (blockIdx.x * blockDim.x + tid) >> 6;
    int lane = tid & 63;
    float bias = b[lane];
    const float* hlane = h_in + lane;
    const unsigned short* hblane = hbf + lane;

    for (int n = wid; n < N; n += totalWaves) {
        int s = rp[n], t = rp[n + 1];
        float self = hlane[(size_t)n * EMBED];  // overlaps with gathers

        float acc0 = 0.f, acc1 = 0.f, acc2 = 0.f, acc3 = 0.f;
        int e = s;
        for (; e + 8 <= t; e += 8) {
            int c0 = col[e+0], c1 = col[e+1], c2 = col[e+2], c3 = col[e+3];
            int c4 = col[e+4], c5 = col[e+5], c6 = col[e+6], c7 = col[e+7];
            float w0 = ew[e+0], w1 = ew[e+1], w2 = ew[e+2], w3 = ew[e+3];
            float w4 = ew[e+4], w5 = ew[e+5], w6 = ew[e+6], w7 = ew[e+7];
            float v0, v1, v2, v3, v4, v5, v6, v7;
            if (USEBF) {
                v0 = __uint_as_float((unsigned)hblane[(size_t)c0 * EMBED] << 16);
                v1 = __uint_as_float((unsigned)hblane[(size_t)c1 * EMBED] << 16);
                v2 = __uint_as_float((unsigned)hblane[(size_t)c2 * EMBED] << 16);
                v3 = __uint_as_float((unsigned)hblane[(size_t)c3 * EMBED] << 16);
                v4 = __uint_as_float((unsigned)hblane[(size_t)c4 * EMBED] << 16);
                v5 = __uint_as_float((unsigned)hblane[(size_t)c5 * EMBED] << 16);
                v6 = __uint_as_float((unsigned)hblane[(size_t)c6 * EMBED] << 16);
                v7 = __uint_as_float((unsigned)hblane[(size_t)c7 * EMBED] << 16);
            } else {
                v0 = hlane[(size_t)c0 * EMBED];
                v1 = hlane[(size_t)c1 * EMBED];
                v2 = hlane[(size_t)c2 * EMBED];
                v3 = hlane[(size_t)c3 * EMBED];
                v4 = hlane[(size_t)c4 * EMBED];
                v5 = hlane[(size_t)c5 * EMBED];
                v6 = hlane[(size_t)c6 * EMBED];
                v7 = hlane[(size_t)c7 * EMBED];
            }
            acc0 = fmaf(w0, v0, acc0);
            acc1 = fmaf(w1, v1, acc1);
            acc2 = fmaf(w2, v2, acc2);
            acc3 = fmaf(w3, v3, acc3);
            acc0 = fmaf(w4, v4, acc0);
            acc1 = fmaf(w5, v5, acc1);
            acc2 = fmaf(w6, v6, acc2);
            acc3 = fmaf(w7, v7, acc3);
        }
        for (; e < t; ++e) {
            float v;
            if (USEBF) v = __uint_as_float((unsigned)hblane[(size_t)col[e] * EMBED] << 16);
            else       v = hlane[(size_t)col[e] * EMBED];
            acc0 = fmaf(ew[e], v, acc0);
        }
        float addv = self + ((acc0 + acc1) + (acc2 + acc3));

        float x = bias;
        #pragma unroll
        for (int jq = 0; jq < 16; ++jq) {
            float4 wv = *(const float4*)&WL[lane * WPAD + jq * 4];
            x = fmaf(__shfl(addv, 4 * jq + 0), wv.x, x);
            x = fmaf(__shfl(addv, 4 * jq + 1), wv.y, x);
            x = fmaf(__shfl(addv, 4 * jq + 2), wv.z, x);
            x = fmaf(__shfl(addv, 4 * jq + 3), wv.w, x);
        }
        x = fmaxf(x, 0.f);

        float ss = x * x;
        #pragma unroll
        for (int off = 32; off > 0; off >>= 1) ss += __shfl_xor(ss, off);
        float nrm = sqrtf(ss);
        float scale = 1.f / fmaxf(nrm, 1e-12f);
        float val = x * scale;
        out[(size_t)n * EMBED + lane] = val;
        if (hbf_out) hbf_out[(size_t)n * EMBED + lane] = f32_to_bf16_rne(val);
    }
}

// out[0] = h0, fallback path only
__global__ void copy_h0_kernel(const float* __restrict__ h0, float* __restrict__ out, int n4) {
    int i = blockIdx.x * blockDim.x + threadIdx.x;
    if (i < n4) ((float4*)out)[i] = ((const float4*)h0)[i];
}

extern "C" void kernel_launch(void* const* d_in, const int* in_sizes, int n_in,
                              void* d_out, int out_size, void* d_ws, size_t ws_size,
                              hipStream_t stream) {
    const float* h0   = (const float*)d_in[0];
    const float* ha   = (const float*)d_in[1];
    const float* ta   = (const float*)d_in[2];
    const float* w1   = (const float*)d_in[3];
    const float* b1   = (const float*)d_in[4];
    const float* w2   = (const float*)d_in[5];
    const float* b2   = (const float*)d_in[6];
    const int*   erow = (const int*)d_in[7];
    const int*   ecol = (const int*)d_in[8];

    const int N = in_sizes[0] / EMBED;
    const int E = in_sizes[7];
    float* out = (float*)d_out;
    float* out1 = out + (size_t)N * EMBED;
    float* out2 = out + 2 * (size_t)N * EMBED;

    // workspace layout
    size_t off = 0;
    auto alloc = [&](size_t bytes) { size_t o = off; off = (off + bytes + 255) & ~(size_t)255; return o; };
    size_t rp_off  = alloc((size_t)(N + 1) * sizeof(int));
    size_t ew_off  = alloc((size_t)E * sizeof(float));
    size_t f32_needed = off;
    size_t h0b_off = alloc((size_t)N * EMBED * 2);
    size_t hab_off = alloc((size_t)N * EMBED * 2);  // reused as h1 bf16 after logits
    size_t tab_off = alloc((size_t)N * EMBED * 2);
    size_t bf_needed = off;

    int*   rp = (int*)((char*)d_ws + rp_off);
    float* ew = (float*)((char*)d_ws + ew_off);

    const bool use_bf = (ws_size >= bf_needed) && ((size_t)ws_size >= f32_needed);
    (void)f32_needed;

    const int blocks = 2048;
    const int totalWaves = blocks * (256 / 64);

    if (use_bf) {
        unsigned int* h0b = (unsigned int*)((char*)d_ws + h0b_off);
        unsigned int* hab = (unsigned int*)((char*)d_ws + hab_off);
        unsigned int* tab = (unsigned int*)((char*)d_ws + tab_off);
        unsigned short* h1b = (unsigned short*)hab;  // alias: hab dead after logits

        int n8 = N * EMBED / 8;
        int cblocks = (n8 + 255) / 256;
        convert_bf16_kernel<<<cblocks, 256, 0, stream>>>(h0, h0b, out, n8);  // fuses out[0]=h0
        convert_bf16_kernel<<<cblocks, 256, 0, stream>>>(ha, hab, nullptr, n8);
        convert_bf16_kernel<<<cblocks, 256, 0, stream>>>(ta, tab, nullptr, n8);

        build_rowptr_kernel<<<(E + 255) / 256, 256, 0, stream>>>(erow, rp, E, N);
        edge_logits_bf16_kernel<<<(E + 255) / 256, 256, 0, stream>>>(hab, tab, erow, ecol, ew, E);
        {
            int wpb = 256 / 64;
            node_softmax_kernel<<<(N + wpb - 1) / wpb, 256, 0, stream>>>(rp, ew, N);
        }
        prop_layer_kernel<true><<<blocks, 256, 0, stream>>>(
            h0, (const unsigned short*)h0b, w1, b1, ecol, ew, rp, out1, h1b, N, totalWaves);
        prop_layer_kernel<true><<<blocks, 256, 0, stream>>>(
            out1, (const unsigned short*)h1b, w2, b2, ecol, ew, rp, out2, nullptr, N, totalWaves);
    } else {
        int n4 = N * EMBED / 4;
        copy_h0_kernel<<<(n4 + 255) / 256, 256, 0, stream>>>(h0, out, n4);
        build_rowptr_kernel<<<(E + 255) / 256, 256, 0, stream>>>(erow, rp, E, N);
        edge_logits_kernel<<<(E + 255) / 256, 256, 0, stream>>>(ha, ta, erow, ecol, ew, E);
        {
            int wpb = 256 / 64;
            node_softmax_kernel<<<(N + wpb - 1) / wpb, 256, 0, stream>>>(rp, ew, N);
        }
        prop_layer_kernel<false><<<blocks, 256, 0, stream>>>(
            h0, nullptr, w1, b1, ecol, ew, rp, out1, nullptr, N, totalWaves);
        prop_layer_kernel<false><<<blocks, 256, 0, stream>>>(
            out1, nullptr, w2, b2, ecol, ew, rp, out2, nullptr, N, totalWaves);
    }
}